// Round 16
// baseline (327.401 us; speedup 1.0000x reference)
//
#include <hip/hip_runtime.h>

// B=512, V=256, W=64, H=64. Outputs: x_tilde_seq (64,512,256) fp32, h_seq (64,512,64) fp32.
// One block = TWO batches (bA, bA+256); 256 blocks x 512 thr, 1 block/CU, 8 waves.
// R13 structure (4 barriers, deferred softmax-r, MFMA gates) + E-ROW IN REGISTERS:
// E is t-invariant and P2's (xj,bsel) identity is fixed -> each thread copies its own
// 64-float E row to 16 float4 regs once after init. Kills P2's 16 b128 E-reads/thread/step
// (the 8-way-conflicted ones; stride-68 pad was tuned for R1's lane=w pattern, not lane=v).
// Register budget: MFMA frags 96 + er 64 + working ~50 < 256 (proven no-spill budget).

#define KLOG2E  1.4426950408889634f   // log2(e)
#define K2LOG2E 2.8853900817779268f   // 2*log2(e)

typedef _Float16 h2    __attribute__((ext_vector_type(2)));
typedef __fp16   f16x8 __attribute__((ext_vector_type(8)));
typedef float    f32x4 __attribute__((ext_vector_type(4)));
union H2U { h2 h; unsigned u; };

__device__ __forceinline__ float frcp(float x)  { return __builtin_amdgcn_rcpf(x); }
__device__ __forceinline__ float fexp2(float x) { return __builtin_amdgcn_exp2f(x); }
__device__ __forceinline__ float fsigmoid(float x) { return frcp(1.f + fexp2(-KLOG2E * x)); }
__device__ __forceinline__ float ftanh(float x) { return 1.f - 2.f * frcp(fexp2(K2LOG2E * x) + 1.f); }

__device__ __forceinline__ unsigned pkrtz_u(float a, float b) {
    H2U r; r.h = __builtin_bit_cast(h2, __builtin_amdgcn_cvt_pkrtz(a, b)); return r.u;
}

// LDS layout (float slots)
#define L_EA   0                    // E_A [256][68] fp32 (init staging + one-time reg copy)
#define L_EB   17408                // E_B [256][68]
#define L_PSA  34816                // gates A [256] (final, r-applied)
#define L_PSB  35072                // gates B [256]
#define L_XHA  35328                // ex packed h2 A [128 u32] (unnormalized)
#define L_XHB  35456
#define L_EWA  35584                // e_w A [64]
#define L_EWB  35648
#define L_HCA  35712                // h||c fp32 A [128]
#define L_HCB  35840
#define L_HHA  35968                // h packed h2 A [32 u32]
#define L_HHB  36000
#define L_BI   36032                // bias b_ih+b_hh [256]
#define L_WV   36288                // -2*w_v [64]
#define L_WS   36352                // wave e-sums [8]: 0-3 = A, 4-7 = B
#define L_TOT  36360                // 145440 bytes <= 160K (1 block/CU)

__global__ __launch_bounds__(512, 2) void enc_kernel(
    const float* __restrict__ x,     // (512,256,64)
    const float* __restrict__ w_ih,  // (256,256)
    const float* __restrict__ w_hh,  // (256,64)
    const float* __restrict__ b_ih,  // (256)
    const float* __restrict__ b_hh,  // (256)
    const float* __restrict__ w_v,   // (64)
    const float* __restrict__ w_w,   // (64,128)
    const float* __restrict__ b_w,   // (64)
    const float* __restrict__ w_u,   // (64,64)
    const float* __restrict__ b_u,   // (64)
    float* __restrict__ out_xt,      // (64,512,256)
    float* __restrict__ out_h)       // (64,512,64)
{
    extern __shared__ float lds[];
    float*    EA   = lds + L_EA;    float*    EB   = lds + L_EB;
    float*    psA  = lds + L_PSA;   float*    psB  = lds + L_PSB;
    unsigned* xhA  = (unsigned*)(lds + L_XHA);
    unsigned* xhB  = (unsigned*)(lds + L_XHB);
    float*    ewA  = lds + L_EWA;   float*    ewB  = lds + L_EWB;
    float*    hcA  = lds + L_HCA;   float*    hcB  = lds + L_HCB;
    unsigned* hhA  = (unsigned*)(lds + L_HHA);
    unsigned* hhB  = (unsigned*)(lds + L_HHB);
    float*    biasL= lds + L_BI;
    float*    wv2L = lds + L_WV;
    float*    wsum = lds + L_WS;

    const int tid  = threadIdx.x;
    const int lane = tid & 63;
    const int wvi  = tid >> 6;            // wave 0..7
    const int bA   = blockIdx.x;
    const int bB   = blockIdx.x + 256;

    // ---- persistent MFMA B-fragments: wave wvi owns gate rows [wvi*32,+32) ----
    // B[k][col]: col = lane&15 (+16 for tile1), k = kk*32 + (lane>>4)*8 + i
    f16x8 wbx0[8], wbx1[8], wbh0[2], wbh1[2];
    {
        const int col0 = wvi*32 + (lane & 15);
        const int col1 = col0 + 16;
        const int kofs = (lane >> 4) * 8;
#pragma unroll
        for (int kk = 0; kk < 8; ++kk) {
            const float* s0 = w_ih + col0*256 + kk*32 + kofs;
            const float* s1 = w_ih + col1*256 + kk*32 + kofs;
            f16x8 a, b;
#pragma unroll
            for (int i = 0; i < 8; ++i) { a[i] = (__fp16)s0[i]; b[i] = (__fp16)s1[i]; }
            wbx0[kk] = a; wbx1[kk] = b;
        }
#pragma unroll
        for (int kk = 0; kk < 2; ++kk) {
            const float* s0 = w_hh + col0*64 + kk*32 + kofs;
            const float* s1 = w_hh + col1*64 + kk*32 + kofs;
            f16x8 a, b;
#pragma unroll
            for (int i = 0; i < 8; ++i) { a[i] = (__fp16)s0[i]; b[i] = (__fp16)s1[i]; }
            wbh0[kk] = a; wbh1[kk] = b;
        }
    }
    // wout: thread (w8 = wvi*8+(lane&7), kg = lane>>3) covers k = kg*4 + 32m (m=0..3)
    const int w8 = wvi*8 + (lane & 7);
    const int kg = lane >> 3;
    float4 www4[4];
#pragma unroll
    for (int m = 0; m < 4; ++m)
        www4[m] = *(const float4*)&w_w[w8*128 + kg*4 + 32*m];
    const float bwr = b_w[w8];
    float Sv = 0.f;
#pragma unroll
    for (int wi = 0; wi < 64; ++wi) Sv += w_v[wi];   // uniform scalar loads
    const float bu_lane = b_u[lane];

    // ---- one-time LDS fills ----
    if (tid < 256) biasL[tid] = b_ih[tid] + b_hh[tid];
    if (tid < 64) wv2L[tid] = -2.f * w_v[tid];
    if (tid < 128) { hcA[tid] = 0.f; hcB[tid] = 0.f; }
    if (tid < 32)  { hhA[tid] = 0u; hhB[tid] = 0u; }

    // ---- E init: E[v][w] = exp(2*(x[b,v,:]@w_u[w,:] + b_u[w])), wave covers 32 rows ----
#pragma unroll 1
    for (int bb = 0; bb < 2; ++bb) {
        float* E = bb ? EB : EA;
        const int b = bb ? bB : bA;
#pragma unroll 1
        for (int half = 0; half < 2; ++half) {
            float4 wu_r[8];
#pragma unroll
            for (int i = 0; i < 8; ++i)
                wu_r[i] = *(const float4*)&w_u[lane*64 + half*32 + 4*i];
            const float* xb = x + b*16384 + half*32;
#pragma unroll 2
            for (int vi = 0; vi < 32; ++vi) {
                int v = __builtin_amdgcn_readfirstlane(wvi*32 + vi);
                const float4* xr = (const float4*)(xb + v*64);
                float acc = 0.f;
#pragma unroll
                for (int i = 0; i < 8; ++i) {
                    float4 xx = xr[i]; float4 wu = wu_r[i];
                    acc += xx.x*wu.x + xx.y*wu.y + xx.z*wu.z + xx.w*wu.w;
                }
                if (half == 0) E[v*68 + lane] = acc + bu_lane;
                else           E[v*68 + lane] = fexp2(K2LOG2E * (E[v*68 + lane] + acc));
            }
        }
    }
    __syncthreads();

    // ---- P2 identity: (xj = tid&255, batch = tid>>8); x_t in a register ----
    const int  xj   = tid & 255;
    const int  bsel = tid >> 8;
    const float* xrow = x + (bsel ? bB : bA)*16384 + xj*64;
    const float* Erow = (bsel ? EB : EA) + xj*68;
    const float* ewX  = bsel ? ewB : ewA;
    unsigned*    xhX  = bsel ? xhB : xhA;
    float xcur = xrow[0];

    // ---- one-time: this thread's E row -> 16 float4 registers (E is t-invariant) ----
    float4 er[16];
#pragma unroll
    for (int q = 0; q < 16; ++q) er[q] = *(const float4*)&Erow[4*q];

    // MFMA lane roles (shared by P1 h-part and P4 x-part)
    const int mrow = lane & 15;          // M-row: 0=A, 1=B, 2-15 zero
    const int q4   = (lane >> 4) * 4;    // u32 offset of this lane's k-group

    for (int t = 0; t < 64; ++t) {
        // ---- P1: wout (VALU) + gates h-part (MFMA) — both read h(t-1) ----
        f32x4 ah0 = {0.f,0.f,0.f,0.f}, ah1 = {0.f,0.f,0.f,0.f};
        {
            float accA = 0.f, accB = 0.f;
#pragma unroll
            for (int m = 0; m < 4; ++m) {
                float4 w4 = www4[m];
                float4 hA = *(const float4*)&hcA[kg*4 + 32*m];
                float4 hB = *(const float4*)&hcB[kg*4 + 32*m];
                accA += hA.x*w4.x + hA.y*w4.y + hA.z*w4.z + hA.w*w4.w;
                accB += hB.x*w4.x + hB.y*w4.y + hB.z*w4.z + hB.w*w4.w;
            }
            const unsigned* hsrc = (mrow == 1) ? hhB : hhA;
#pragma unroll
            for (int kk = 0; kk < 2; ++kk) {
                f16x8 a = {};
                if (mrow < 2)
                    a = __builtin_bit_cast(f16x8, *(const uint4*)(hsrc + kk*16 + q4));
                ah0 = __builtin_amdgcn_mfma_f32_16x16x32_f16(a, wbh0[kk], ah0, 0, 0, 0);
                ah1 = __builtin_amdgcn_mfma_f32_16x16x32_f16(a, wbh1[kk], ah1, 0, 0, 0);
            }
#pragma unroll
            for (int off = 8; off <= 32; off <<= 1) {
                accA += __shfl_xor(accA, off, 64);
                accB += __shfl_xor(accB, off, 64);
            }
            if (kg == 0)      ewA[w8] = fexp2(K2LOG2E * (accA + bwr));
            else if (kg == 1) ewB[w8] = fexp2(K2LOG2E * (accB + bwr));
        }
        float xnxt = (t < 63) ? xrow[t + 1] : 0.f;   // prefetch; latency spans B1+P2
        __syncthreads();   // B1

        // ---- P2: score from REGISTER E; e, ex; wave e-sums; pack unnormalized ex ----
        float exreg;
        {
            float ac0 = 0.f, ac1 = 0.f, ac2 = 0.f, ac3 = 0.f;
#pragma unroll
            for (int q = 0; q < 16; ++q) {
                float4 e4 = er[q];                        // registers (was 8-way-conflict LDS)
                float4 c4 = *(const float4*)&ewX[4*q];    // broadcast
                float4 v4 = *(const float4*)&wv2L[4*q];   // broadcast
                ac0 += v4.x * frcp(e4.x*c4.x + 1.f);
                ac1 += v4.y * frcp(e4.y*c4.y + 1.f);
                ac2 += v4.z * frcp(e4.z*c4.z + 1.f);
                ac3 += v4.w * frcp(e4.w*c4.w + 1.f);
            }
            float acc = Sv + ((ac0 + ac1) + (ac2 + ac3));
            float e  = fexp2(KLOG2E * acc);  // |score| <= sum|w_v| ~2.6: no max-subtract
            exreg = e * xcur;
            float s = e;
#pragma unroll
            for (int off = 1; off <= 32; off <<= 1) s += __shfl_xor(s, off, 64);
            if (lane == 0) wsum[wvi] = s;
            float ex2 = __shfl_xor(exreg, 1, 64);
            if (!(lane & 1)) xhX[xj >> 1] = pkrtz_u(exreg, ex2);   // stride-1: conflict-free
        }
        xcur = xnxt;
        __syncthreads();   // B2

        // ---- P4: r from wsum; out_xt = r*ex_reg; gates x-part MFMA; ps = r*ax + ah ----
        {
            float rA = frcp((wsum[0] + wsum[1]) + (wsum[2] + wsum[3]));
            float rB = frcp((wsum[4] + wsum[5]) + (wsum[6] + wsum[7]));
            out_xt[t*131072 + (bsel ? bB : bA)*256 + xj] = (bsel ? rB : rA) * exreg;

            f32x4 ax0 = {0.f,0.f,0.f,0.f}, ax1 = {0.f,0.f,0.f,0.f};
            const unsigned* xsrc = (mrow == 1) ? xhB : xhA;
#pragma unroll
            for (int kk = 0; kk < 8; ++kk) {
                f16x8 a = {};
                if (mrow < 2)
                    a = __builtin_bit_cast(f16x8, *(const uint4*)(xsrc + kk*16 + q4));
                ax0 = __builtin_amdgcn_mfma_f32_16x16x32_f16(a, wbx0[kk], ax0, 0, 0, 0);
                ax1 = __builtin_amdgcn_mfma_f32_16x16x32_f16(a, wbx1[kk], ax1, 0, 0, 0);
            }
            // D: col = lane&15 (gate row), rows 0/1 = batch A/B in regs 0/1
            if (lane < 16) {
                const int j0 = wvi*32 + lane, j1 = j0 + 16;
                psA[j0] = rA*ax0[0] + ah0[0];
                psA[j1] = rA*ax1[0] + ah1[0];
                psB[j0] = rB*ax0[1] + ah0[1];
                psB[j1] = rB*ax1[1] + ah1[1];
            }
        }
        __syncthreads();   // B3

        // ---- P5: LSTM cell (wave0 = A, wave1 = B); gates already reduced ----
        if (wvi < 2) {
            float*    ps = wvi ? psB : psA;
            float*    hc = wvi ? hcB : hcA;
            unsigned* hh = wvi ? hhB : hhA;
            float*    oh = out_h + t*32768 + (wvi ? bB : bA)*64;
            const int k = lane;
            float gi = fsigmoid(biasL[k      ] + ps[k      ]);
            float gf = fsigmoid(biasL[64  + k] + ps[64  + k]);
            float gg = ftanh   (biasL[128 + k] + ps[128 + k]);
            float go = fsigmoid(biasL[192 + k] + ps[192 + k]);
            float cn = gf * hc[64 + k] + gi * gg;
            float hn = go * ftanh(cn);
            hc[k] = hn; hc[64 + k] = cn;
            float hp = __shfl_xor(hn, 1, 64);
            if (!(lane & 1)) hh[k >> 1] = pkrtz_u(hn, hp);
            oh[k] = hn;
        }
        __syncthreads();   // B4
    }
}

extern "C" void kernel_launch(void* const* d_in, const int* in_sizes, int n_in,
                              void* d_out, int out_size, void* d_ws, size_t ws_size,
                              hipStream_t stream) {
    const float* x    = (const float*)d_in[0];
    const float* w_ih = (const float*)d_in[1];
    const float* w_hh = (const float*)d_in[2];
    const float* b_ih = (const float*)d_in[3];
    const float* b_hh = (const float*)d_in[4];
    const float* w_v  = (const float*)d_in[5];
    const float* w_w  = (const float*)d_in[6];
    const float* b_w  = (const float*)d_in[7];
    const float* w_u  = (const float*)d_in[8];
    const float* b_u  = (const float*)d_in[9];

    float* out_xt = (float*)d_out;
    float* out_h  = out_xt + 64*512*256;

    const size_t shbytes = (size_t)L_TOT * sizeof(float);  // 145440 B
    (void)hipFuncSetAttribute((const void*)enc_kernel,
                        hipFuncAttributeMaxDynamicSharedMemorySize, (int)shbytes);
    enc_kernel<<<dim3(256), dim3(512), shbytes, stream>>>(
        x, w_ih, w_hh, b_ih, b_hh, w_v, w_w, b_w, w_u, b_u, out_xt, out_h);
}

// Round 17
// 275.368 us; speedup vs baseline: 1.1890x; 1.1890x over previous
//
#include <hip/hip_runtime.h>

// B=512, V=256, W=64, H=64. Outputs: x_tilde_seq (64,512,256) fp32, h_seq (64,512,64) fp32.
// One block = TWO batches; 256 blocks x 1024 thr = 16 waves = 4 waves/SIMD, 1 block/CU.
// Breaking the 8-wave wall WITHOUT weight duplication: single barrier domain holds ONE
// copy of w_ih, split per-wave to 1 N-tile: kk0-3 fragments in regs (16), kk4-7 in LDS
// as lane-linear uint4 frags (64KB, clean ds_read_b128); w_hh in regs (8); w_w (4).
// ~85 live regs <= 128 budget (launch_bounds(1024,4)). E stored fp16-packed (73.7KB).
// Step: P1 wout | B1 | P2 score half-rows | B2 | P4 r + out_xt + gates MFMA | B3 | P5 cell | B4.

#define KLOG2E  1.4426950408889634f   // log2(e)
#define K2LOG2E 2.8853900817779268f   // 2*log2(e)

typedef _Float16 h2    __attribute__((ext_vector_type(2)));
typedef __fp16   f16x8 __attribute__((ext_vector_type(8)));
typedef float    f32x4 __attribute__((ext_vector_type(4)));
union H2U { h2 h; unsigned u; };

__device__ __forceinline__ float frcp(float x)  { return __builtin_amdgcn_rcpf(x); }
__device__ __forceinline__ float fexp2(float x) { return __builtin_amdgcn_exp2f(x); }
__device__ __forceinline__ float fsigmoid(float x) { return frcp(1.f + fexp2(-KLOG2E * x)); }
__device__ __forceinline__ float ftanh(float x) { return 1.f - 2.f * frcp(fexp2(K2LOG2E * x) + 1.f); }

__device__ __forceinline__ unsigned pkrtz_u(float a, float b) {
    H2U r; r.h = __builtin_bit_cast(h2, __builtin_amdgcn_cvt_pkrtz(a, b)); return r.u;
}
__device__ __forceinline__ h2 pk_rtn(float a, float b) {   // round-to-nearest (weights/E)
    h2 r; r.x = (_Float16)a; r.y = (_Float16)b; return r;
}
__device__ __forceinline__ unsigned pk_rtn_u(float a, float b) {
    H2U r; r.h = pk_rtn(a, b); return r.u;
}

// LDS layout (float slots)
#define L_EHA  0                    // E_A fp16-packed: [256][36] u32 (w-pairs, stride 36)
#define L_EHB  9216
#define L_WF   18432                // w_ih kk4-7 B-frags: [16 wvi][4 kk][64 lane] uint4 = 64KB
#define L_PSA  34816                // gates A [256] (final)
#define L_PSB  35072
#define L_XHA  35328                // ex packed h2 A [128 u32]
#define L_XHB  35456
#define L_EWA  35584                // e_w A [64] fp32
#define L_EWB  35648
#define L_HCA  35712                // h||c fp32 A [128]
#define L_HCB  35840
#define L_HHA  35968                // h packed h2 A [32 u32]
#define L_HHB  36000
#define L_BI   36032                // bias b_ih+b_hh [256]
#define L_WV   36288                // -2*w_v [64]
#define L_WS   36352                // wave e-sums [16]: 0-7 = A, 8-15 = B
#define L_TOT  36368                // 145472 bytes <= 160K (1 block/CU)

__global__ __launch_bounds__(1024, 4) void enc_kernel(
    const float* __restrict__ x,     // (512,256,64)
    const float* __restrict__ w_ih,  // (256,256)
    const float* __restrict__ w_hh,  // (256,64)
    const float* __restrict__ b_ih,  // (256)
    const float* __restrict__ b_hh,  // (256)
    const float* __restrict__ w_v,   // (64)
    const float* __restrict__ w_w,   // (64,128)
    const float* __restrict__ b_w,   // (64)
    const float* __restrict__ w_u,   // (64,64)
    const float* __restrict__ b_u,   // (64)
    float* __restrict__ out_xt,      // (64,512,256)
    float* __restrict__ out_h)       // (64,512,64)
{
    extern __shared__ float lds[];
    unsigned* EHA  = (unsigned*)(lds + L_EHA);
    unsigned* EHB  = (unsigned*)(lds + L_EHB);
    uint4*    WF4  = (uint4*)(lds + L_WF);
    float*    psA  = lds + L_PSA;   float* psB = lds + L_PSB;
    unsigned* xhA  = (unsigned*)(lds + L_XHA);
    unsigned* xhB  = (unsigned*)(lds + L_XHB);
    float*    ewA  = lds + L_EWA;   float* ewB = lds + L_EWB;
    float*    hcA  = lds + L_HCA;   float* hcB = lds + L_HCB;
    unsigned* hhA  = (unsigned*)(lds + L_HHA);
    unsigned* hhB  = (unsigned*)(lds + L_HHB);
    float*    biasL= lds + L_BI;
    float*    wv2L = lds + L_WV;
    float*    wsum = lds + L_WS;

    const int tid  = threadIdx.x;        // 0..1023
    const int lane = tid & 63;
    const int wvi  = tid >> 6;           // wave 0..15
    const int bA   = blockIdx.x;
    const int bB   = blockIdx.x + 256;

    // ---- MFMA fragment identity: wave wvi owns N-tile cols [wvi*16,+16) ----
    const int colw = wvi*16 + (lane & 15);
    const int kofs = (lane >> 4) * 8;

    // ---- P1 identity: w8 = wvi*4+(lane>>4), kg = lane&15 covers k = kg*4..+4 ----
    const int w8 = wvi*4 + (lane >> 4);
    const int kg = lane & 15;
    const float4 www4 = *(const float4*)&w_w[w8*128 + kg*4];
    const float bwr = b_w[w8];
    float Sv = 0.f;
#pragma unroll
    for (int wi = 0; wi < 64; ++wi) Sv += w_v[wi];   // uniform scalar loads
    const float bu_lane = b_u[lane];

    // ---- one-time small LDS fills ----
    if (tid < 256) biasL[tid] = b_ih[tid] + b_hh[tid];
    if (tid < 64)  wv2L[tid] = -2.f * w_v[tid];
    if (tid < 128) { hcA[tid] = 0.f; hcB[tid] = 0.f; }
    if (tid < 32)  { hhA[tid] = 0u; hhB[tid] = 0u; }

    // ---- E init: E[v][w]=exp(2*(x[b,v,:]@w_u[w,:]+b_u[w])) -> fp16-packed rows ----
    // wave covers rows [wvi*16,+16) per batch; lane = w. a0[16] regs stash half0.
#pragma unroll 1
    for (int bb = 0; bb < 2; ++bb) {
        unsigned* EH = bb ? EHB : EHA;
        const int b = bb ? bB : bA;
        float a0[16];
        {
            float4 wu_r[8];
#pragma unroll
            for (int i = 0; i < 8; ++i) wu_r[i] = *(const float4*)&w_u[lane*64 + 4*i];
            const float* xb = x + b*16384;
#pragma unroll 2
            for (int vi = 0; vi < 16; ++vi) {
                int v = __builtin_amdgcn_readfirstlane(wvi*16 + vi);
                const float4* xr = (const float4*)(xb + v*64);
                float acc = 0.f;
#pragma unroll
                for (int i = 0; i < 8; ++i) {
                    float4 xx = xr[i]; float4 wu = wu_r[i];
                    acc += xx.x*wu.x + xx.y*wu.y + xx.z*wu.z + xx.w*wu.w;
                }
                a0[vi] = acc;
            }
        }
        {
            float4 wu_r[8];
#pragma unroll
            for (int i = 0; i < 8; ++i) wu_r[i] = *(const float4*)&w_u[lane*64 + 32 + 4*i];
            const float* xb = x + b*16384 + 32;
#pragma unroll 2
            for (int vi = 0; vi < 16; ++vi) {
                int v = __builtin_amdgcn_readfirstlane(wvi*16 + vi);
                const float4* xr = (const float4*)(xb + v*64);
                float acc = a0[vi] + bu_lane;
#pragma unroll
                for (int i = 0; i < 8; ++i) {
                    float4 xx = xr[i]; float4 wu = wu_r[i];
                    acc += xx.x*wu.x + xx.y*wu.y + xx.z*wu.z + xx.w*wu.w;
                }
                float e = fexp2(K2LOG2E * acc);        // E in [e^-6, e^6]: fp16-safe
                float e2 = __shfl_xor(e, 1, 64);
                if (!(lane & 1)) EH[v*36 + (lane >> 1)] = pk_rtn_u(e, e2);
            }
        }
    }

    // ---- persistent B-frags (regs): w_ih kk0-3, w_hh kk0-1; stage kk4-7 into LDS ----
    f16x8 wbx[4], wbh[2];
#pragma unroll
    for (int kk = 0; kk < 4; ++kk) {
        const float* s = w_ih + colw*256 + kk*32 + kofs;
        f16x8 a;
#pragma unroll
        for (int i = 0; i < 8; ++i) a[i] = (__fp16)s[i];
        wbx[kk] = a;
    }
#pragma unroll
    for (int kk = 0; kk < 2; ++kk) {
        const float* s = w_hh + colw*64 + kk*32 + kofs;
        f16x8 a;
#pragma unroll
        for (int i = 0; i < 8; ++i) a[i] = (__fp16)s[i];
        wbh[kk] = a;
    }
#pragma unroll
    for (int kk = 4; kk < 8; ++kk) {
        const float* s = w_ih + colw*256 + kk*32 + kofs;
        uint4 u;
        u.x = pk_rtn_u(s[0], s[1]);
        u.y = pk_rtn_u(s[2], s[3]);
        u.z = pk_rtn_u(s[4], s[5]);
        u.w = pk_rtn_u(s[6], s[7]);
        WF4[(wvi*4 + (kk - 4))*64 + lane] = u;      // lane-linear: clean b128 on read
    }
    __syncthreads();

    // ---- P2 identity: bsel = tid>>9 (waves 0-7 = A, 8-15 = B); half-rows ----
    const int xj   = (tid & 511) >> 1;   // v row 0..255
    const int hf   = tid & 1;            // w-half
    const int bsel = tid >> 9;
    const uint4* EHrow4 = (const uint4*)((bsel ? EHB : EHA) + xj*36 + hf*16);
    const float* ewS = (bsel ? ewB : ewA) + hf*32;
    const float* wvS = wv2L + hf*32;
    unsigned*    xhX = bsel ? xhB : xhA;
    const float  SvIni = hf ? 0.f : Sv;
    const float* xrow = x + (bsel ? bB : bA)*16384 + xj*64;
    float xcur = hf ? 0.f : xrow[0];

    // MFMA lane roles
    const int mrow = lane & 15;          // M-row: 0=A, 1=B, 2-15 zero
    const int q4   = (lane >> 4) * 4;    // u32 offset of this lane's k-group

    for (int t = 0; t < 64; ++t) {
        // ---- P1: wout for both batches (16 lanes per w; 4-level shfl reduce) ----
        {
            float4 hA = *(const float4*)&hcA[kg*4];
            float4 hB = *(const float4*)&hcB[kg*4];
            float accA = hA.x*www4.x + hA.y*www4.y + hA.z*www4.z + hA.w*www4.w;
            float accB = hB.x*www4.x + hB.y*www4.y + hB.z*www4.z + hB.w*www4.w;
#pragma unroll
            for (int off = 1; off <= 8; off <<= 1) {
                accA += __shfl_xor(accA, off, 64);
                accB += __shfl_xor(accB, off, 64);
            }
            if (kg == 0)      ewA[w8] = fexp2(K2LOG2E * (accA + bwr));
            else if (kg == 1) ewB[w8] = fexp2(K2LOG2E * (accB + bwr));
        }
        float xnxt = (hf == 0 && t < 63) ? xrow[t + 1] : 0.f;   // prefetch across B1
        __syncthreads();   // B1

        // ---- P2: score half-row (32 rcp) from fp16 E; combine halves; e-sums ----
        float exreg;
        {
            float ac0 = SvIni, ac1 = 0.f, ac2 = 0.f, ac3 = 0.f;
#pragma unroll
            for (int i = 0; i < 4; ++i) {
                uint4 U = EHrow4[i];
                float4 c0 = *(const float4*)&ewS[8*i];
                float4 c1 = *(const float4*)&ewS[8*i + 4];
                float4 v0 = *(const float4*)&wvS[8*i];
                float4 v1 = *(const float4*)&wvS[8*i + 4];
                H2U u0, u1, u2, u3;
                u0.u = U.x; u1.u = U.y; u2.u = U.z; u3.u = U.w;
                ac0 += v0.x * frcp((float)u0.h.x * c0.x + 1.f);
                ac1 += v0.y * frcp((float)u0.h.y * c0.y + 1.f);
                ac2 += v0.z * frcp((float)u1.h.x * c0.z + 1.f);
                ac3 += v0.w * frcp((float)u1.h.y * c0.w + 1.f);
                ac0 += v1.x * frcp((float)u2.h.x * c1.x + 1.f);
                ac1 += v1.y * frcp((float)u2.h.y * c1.y + 1.f);
                ac2 += v1.z * frcp((float)u3.h.x * c1.z + 1.f);
                ac3 += v1.w * frcp((float)u3.h.y * c1.w + 1.f);
            }
            float acc = (ac0 + ac1) + (ac2 + ac3);
            acc += __shfl_xor(acc, 1, 64);               // combine w-halves (hf pair)
            float e = fexp2(KLOG2E * acc);   // |score| <= sum|w_v| ~2.6: no max-subtract
            exreg = e * xcur;                            // valid in hf==0 lanes
            float s = e;                                 // each row counted once (stride>=2)
            s += __shfl_xor(s, 2, 64);  s += __shfl_xor(s, 4, 64);
            s += __shfl_xor(s, 8, 64);  s += __shfl_xor(s, 16, 64);
            s += __shfl_xor(s, 32, 64);
            if (lane == 0) wsum[wvi] = s;
            float exhi = __shfl_xor(exreg, 2, 64);       // next row's ex
            if ((lane & 3) == 0) xhX[xj >> 1] = pkrtz_u(exreg, exhi);
        }
        xcur = xnxt;
        __syncthreads();   // B2

        // ---- P4: r; out_xt = r*ex_reg; gates MFMA (x: 4 reg-frag + 4 LDS-frag; h: 2) ----
        {
            float rA = frcp(((wsum[0] + wsum[1]) + (wsum[2] + wsum[3]))
                          + ((wsum[4] + wsum[5]) + (wsum[6] + wsum[7])));
            float rB = frcp(((wsum[8] + wsum[9]) + (wsum[10] + wsum[11]))
                          + ((wsum[12] + wsum[13]) + (wsum[14] + wsum[15])));
            if (hf == 0)
                out_xt[t*131072 + (bsel ? bB : bA)*256 + xj] = (bsel ? rB : rA) * exreg;

            f32x4 ax = {0.f,0.f,0.f,0.f}, ah = {0.f,0.f,0.f,0.f};
            const unsigned* xsrc = (mrow == 1) ? xhB : xhA;
#pragma unroll
            for (int kk = 0; kk < 8; ++kk) {
                f16x8 a = {};
                if (mrow < 2)
                    a = __builtin_bit_cast(f16x8, *(const uint4*)(xsrc + kk*16 + q4));
                f16x8 bf;
                if (kk < 4) bf = wbx[kk];
                else        bf = __builtin_bit_cast(f16x8, WF4[(wvi*4 + (kk - 4))*64 + lane]);
                ax = __builtin_amdgcn_mfma_f32_16x16x32_f16(a, bf, ax, 0, 0, 0);
            }
            const unsigned* hsrc = (mrow == 1) ? hhB : hhA;
#pragma unroll
            for (int kk = 0; kk < 2; ++kk) {
                f16x8 a = {};
                if (mrow < 2)
                    a = __builtin_bit_cast(f16x8, *(const uint4*)(hsrc + kk*16 + q4));
                ah = __builtin_amdgcn_mfma_f32_16x16x32_f16(a, wbh[kk], ah, 0, 0, 0);
            }
            // D: col = lane&15 (gate row within tile), rows 0/1 = batch A/B in regs 0/1
            if (lane < 16) {
                psA[wvi*16 + lane] = rA*ax[0] + ah[0];
                psB[wvi*16 + lane] = rB*ax[1] + ah[1];
            }
        }
        __syncthreads();   // B3

        // ---- P5: LSTM cell (wave0 = A, wave1 = B); gates already reduced ----
        if (wvi < 2) {
            float*    ps = wvi ? psB : psA;
            float*    hc = wvi ? hcB : hcA;
            unsigned* hh = wvi ? hhB : hhA;
            float*    oh = out_h + t*32768 + (wvi ? bB : bA)*64;
            const int k = lane;
            float gi = fsigmoid(biasL[k      ] + ps[k      ]);
            float gf = fsigmoid(biasL[64  + k] + ps[64  + k]);
            float gg = ftanh   (biasL[128 + k] + ps[128 + k]);
            float go = fsigmoid(biasL[192 + k] + ps[192 + k]);
            float cn = gf * hc[64 + k] + gi * gg;
            float hn = go * ftanh(cn);
            hc[k] = hn; hc[64 + k] = cn;
            float hp = __shfl_xor(hn, 1, 64);
            if (!(lane & 1)) hh[k >> 1] = pkrtz_u(hn, hp);
            oh[k] = hn;
        }
        __syncthreads();   // B4
    }
}

extern "C" void kernel_launch(void* const* d_in, const int* in_sizes, int n_in,
                              void* d_out, int out_size, void* d_ws, size_t ws_size,
                              hipStream_t stream) {
    const float* x    = (const float*)d_in[0];
    const float* w_ih = (const float*)d_in[1];
    const float* w_hh = (const float*)d_in[2];
    const float* b_ih = (const float*)d_in[3];
    const float* b_hh = (const float*)d_in[4];
    const float* w_v  = (const float*)d_in[5];
    const float* w_w  = (const float*)d_in[6];
    const float* b_w  = (const float*)d_in[7];
    const float* w_u  = (const float*)d_in[8];
    const float* b_u  = (const float*)d_in[9];

    float* out_xt = (float*)d_out;
    float* out_h  = out_xt + 64*512*256;

    const size_t shbytes = (size_t)L_TOT * sizeof(float);  // 145472 B
    (void)hipFuncSetAttribute((const void*)enc_kernel,
                        hipFuncAttributeMaxDynamicSharedMemorySize, (int)shbytes);
    enc_kernel<<<dim3(256), dim3(1024), shbytes, stream>>>(
        x, w_ih, w_hh, b_ih, b_hh, w_v, w_w, b_w, w_u, b_u, out_xt, out_h);
}